// Round 5
// baseline (314.249 us; speedup 1.0000x reference)
//
#include <hip/hip_runtime.h>
#include <hip/hip_cooperative_groups.h>

namespace cg = cooperative_groups;

#define B 8
#define NH 512
#define D 128
#define HEADS 4
#define ALPHA 0.2f

typedef short short8 __attribute__((ext_vector_type(8)));
typedef float f32x4 __attribute__((ext_vector_type(4)));
typedef unsigned short u16t;

__device__ __forceinline__ unsigned short f2b(float f) {
    union { float f; unsigned u; } v; v.f = f;
    unsigned r = v.u + 0x7FFFu + ((v.u >> 16) & 1u);
    return (unsigned short)(r >> 16);
}
__device__ __forceinline__ float lrelu(float x) { return fmaxf(x, ALPHA * x); }
// pack two f32 -> two bf16 (truncation) in one v_perm
__device__ __forceinline__ unsigned packbf(float a, float b) {
    union { float f; unsigned u; } ua, ub; ua.f = a; ub.f = b;
    return __builtin_amdgcn_perm(ub.u, ua.u, 0x07060302u);
}

// ===================== phase bodies (shared by coop + fallback) ============

// gi in [0, 131072): WhT for gi<64K, WoT for gi>=64K, 8 xb elems each
__device__ __forceinline__ void prep_body(int gi,
    const float* __restrict__ hs, const float* __restrict__ os,
    const float* __restrict__ Wh, const float* __restrict__ Wo,
    u16t* __restrict__ WhT, u16t* __restrict__ WoT, u16t* __restrict__ xb)
{
    if (gi < 65536) {
        int h = gi >> 14, rem = gi & 16383, c = rem >> 7, k = rem & 127;
        WhT[gi] = f2b(Wh[(h * 128 + k) * 128 + c]);
    } else {
        int i2 = gi - 65536;
        int c = i2 >> 9, k = i2 & 511;
        WoT[i2] = f2b(Wo[k * 128 + c]);
    }
    {
        size_t base = (size_t)gi * 8;
        int row = (int)(base >> 7), col = (int)(base & 127);
        int b = row >> 10, n = row & 1023;
        const float* src = (n < NH) ? hs + ((size_t)(b * NH + n)) * 128 + col
                                    : os + ((size_t)(b * NH + (n - NH))) * 128 + col;
        u16t* dst = xb + base;
        #pragma unroll
        for (int q = 0; q < 8; q += 4) {
            float4 v = *(const float4*)(src + q);
            dst[q + 0] = f2b(v.x); dst[q + 1] = f2b(v.y);
            dst[q + 2] = f2b(v.z); dst[q + 3] = f2b(v.w);
        }
    }
}

// bid in [0,512): rt=bid>>2 (64-row tile), h=bid&3
__device__ __forceinline__ void proj1_body(int bid, int t,
    const u16t* __restrict__ xb, const u16t* __restrict__ WhT,
    const float* __restrict__ ah,
    u16t* __restrict__ h1T, float* __restrict__ f1, float* __restrict__ f2)
{
    int rt = bid >> 2, h = bid & 3;
    int rowG = rt * 64;
    int b = rowG >> 10;
    int w = t >> 6, l = t & 63, l15 = l & 15, g = l >> 4;

    int nA = rowG + w * 16 + l15;
    const u16t* WTh = WhT + (size_t)h * 16384;

    f32x4 acc[8] = {};
    #pragma unroll
    for (int kc = 0; kc < 4; ++kc) {
        int k0 = kc * 32 + g * 8;
        short8 af = *(const short8*)&xb[(size_t)nA * 128 + k0];
        #pragma unroll
        for (int ct = 0; ct < 8; ++ct) {
            short8 bfr = *(const short8*)&WTh[(ct * 16 + l15) * 128 + k0];
            acc[ct] = __builtin_amdgcn_mfma_f32_16x16x32_bf16(af, bfr, acc[ct], 0, 0, 0);
        }
    }

    int bh = b * HEADS + h;
    size_t hTbase = (size_t)bh * 131072;
    int nloc0 = (rowG & 1023) + w * 16 + g * 4;
    float pr1[4] = {0.f, 0.f, 0.f, 0.f}, pr2[4] = {0.f, 0.f, 0.f, 0.f};

    #pragma unroll
    for (int ct = 0; ct < 8; ++ct) {
        int c = ct * 16 + l15;
        unsigned long long pv =
              (unsigned long long)f2b(acc[ct][0])
            | ((unsigned long long)f2b(acc[ct][1]) << 16)
            | ((unsigned long long)f2b(acc[ct][2]) << 32)
            | ((unsigned long long)f2b(acc[ct][3]) << 48);
        *(unsigned long long*)&h1T[hTbase + (size_t)c * 1024 + nloc0] = pv;
        float a1 = ah[h * 256 + c], a2 = ah[h * 256 + 128 + c];
        #pragma unroll
        for (int r = 0; r < 4; ++r) {
            pr1[r] = fmaf(acc[ct][r], a1, pr1[r]);
            pr2[r] = fmaf(acc[ct][r], a2, pr2[r]);
        }
    }
    #pragma unroll
    for (int r = 0; r < 4; ++r) {
        float v1 = pr1[r], v2 = pr2[r];
        #pragma unroll
        for (int m = 1; m <= 8; m <<= 1) {
            v1 += __shfl_xor(v1, m, 64);
            v2 += __shfl_xor(v2, m, 64);
        }
        if (l15 == 0) {
            f1[(size_t)bh * 1024 + nloc0 + r] = v1;
            f2[(size_t)bh * 1024 + nloc0 + r] = v2;
        }
    }
}

// bid in [0,128): 64-row tile of the 8192 x2 rows
__device__ __forceinline__ void proj2_body(int bid, int t,
    const u16t* __restrict__ x2, const u16t* __restrict__ WoT,
    const float* __restrict__ ao,
    u16t* __restrict__ h2T, float* __restrict__ f1, float* __restrict__ f2)
{
    int rowG = bid * 64;
    int b = rowG >> 10;
    int w = t >> 6, l = t & 63, l15 = l & 15, g = l >> 4;

    int rowA = rowG + w * 16 + l15;

    f32x4 acc[8] = {};
    #pragma unroll
    for (int kc = 0; kc < 16; ++kc) {
        int k0 = kc * 32 + g * 8;
        short8 af = *(const short8*)&x2[(size_t)rowA * 512 + k0];
        #pragma unroll
        for (int ct = 0; ct < 8; ++ct) {
            short8 bfr = *(const short8*)&WoT[(ct * 16 + l15) * 512 + k0];
            acc[ct] = __builtin_amdgcn_mfma_f32_16x16x32_bf16(af, bfr, acc[ct], 0, 0, 0);
        }
    }

    size_t hTbase = (size_t)b * 131072;
    int nloc0 = (rowG & 1023) + w * 16 + g * 4;
    int rowOut0 = rowG + w * 16 + g * 4;
    float pr1[4] = {0.f, 0.f, 0.f, 0.f}, pr2[4] = {0.f, 0.f, 0.f, 0.f};

    #pragma unroll
    for (int ct = 0; ct < 8; ++ct) {
        int c = ct * 16 + l15;
        unsigned long long pv =
              (unsigned long long)f2b(acc[ct][0])
            | ((unsigned long long)f2b(acc[ct][1]) << 16)
            | ((unsigned long long)f2b(acc[ct][2]) << 32)
            | ((unsigned long long)f2b(acc[ct][3]) << 48);
        *(unsigned long long*)&h2T[hTbase + (size_t)c * 1024 + nloc0] = pv;
        float a1 = ao[c], a2 = ao[128 + c];
        #pragma unroll
        for (int r = 0; r < 4; ++r) {
            pr1[r] = fmaf(acc[ct][r], a1, pr1[r]);
            pr2[r] = fmaf(acc[ct][r], a2, pr2[r]);
        }
    }
    #pragma unroll
    for (int r = 0; r < 4; ++r) {
        float v1 = pr1[r], v2 = pr2[r];
        #pragma unroll
        for (int m = 1; m <= 8; m <<= 1) {
            v1 += __shfl_xor(v1, m, 64);
            v2 += __shfl_xor(v2, m, 64);
        }
        if (l15 == 0) { f1[rowOut0 + r] = v1; f2[rowOut0 + r] = v2; }
    }
}

// mode 0: wid in [0,512) XCD-swizzled; mode 1: wid in [0,64)
__device__ __forceinline__ void attn_body(int mode, int wid, int t,
    const u16t* __restrict__ HT,
    const float* __restrict__ f1, const float* __restrict__ f2,
    u16t* __restrict__ x2, float* __restrict__ dout,
    u16t (&hbuf)[2][128][40], float (&f2s)[512], float (&red4)[4])
{
    int w4 = t >> 6, l = t & 63, l15 = l & 15, g = l >> 4;
    int itile, side, z, b, h;
    if (mode == 0) {
        int xcd = wid & 7, jj = (wid >> 3) & 7;
        itile = wid >> 6;
        int q = xcd * 8 + jj;
        z = q >> 1; side = q & 1; b = z >> 2; h = z & 3;
    } else {
        b = wid & 7; itile = wid >> 3; side = 0; z = b; h = 0;
    }
    bool self = (side == 0);
    int nbBase = self ? 512 : 0;
    size_t HTbase = (size_t)z * 131072;
    size_t fbase = (size_t)z * 1024;

    f2s[t] = f2[fbase + nbBase + t];
    f2s[t + 256] = f2[fbase + nbBase + t + 256];
    __syncthreads();
    float mv = fmaxf(f2s[t], f2s[t + 256]);
    #pragma unroll
    for (int m = 1; m <= 32; m <<= 1) mv = fmaxf(mv, __shfl_xor(mv, m, 64));
    if (l == 0) red4[w4] = mv;
    __syncthreads();
    float M = fmaxf(fmaxf(red4[0], red4[1]), fmaxf(red4[2], red4[3]));

    int i0 = itile * 64 + w4 * 16;
    int i = i0 + l15;
    int n = side * 512 + i;
    float fv = f1[fbase + n];
    float mr = lrelu(fv + M);
    float z0 = 0.f;
    if (self) {
        float sc = lrelu(fv + f2[fbase + i]);
        mr = fmaxf(mr, sc);
        z0 = __expf(sc - mr);
    }
    float zacc = (g == 0) ? z0 : 0.f;

    {
        int c = t >> 1, ks = (t & 1) * 16;
        const u16t* src = &HT[HTbase + (size_t)c * 1024 + nbBase + ks];
        *(short8*)&hbuf[0][c][ks] = *(const short8*)src;
        *(short8*)&hbuf[0][c][ks + 8] = *(const short8*)(src + 8);
    }
    __syncthreads();

    f32x4 acc[8] = {};
    int cS = t >> 1, ksS = (t & 1) * 16;

    for (int jt = 0; jt < 16; ++jt) {
        int cur = jt & 1;
        short8 s0, s1;
        if (jt < 15) {
            const u16t* src = &HT[HTbase + (size_t)cS * 1024 + nbBase + (jt + 1) * 32 + ksS];
            s0 = *(const short8*)src;
            s1 = *(const short8*)(src + 8);
        }
        int j0 = jt * 32 + g * 8;
        float p[8];
        #pragma unroll
        for (int q = 0; q < 8; ++q) {
            float tq = fv + f2s[j0 + q];
            float ev = fmaxf(tq, ALPHA * tq);
            p[q] = __expf(ev - mr);
            zacc += p[q];
        }
        union { unsigned u[4]; short8 s; } pfu;
        pfu.u[0] = packbf(p[0], p[1]);
        pfu.u[1] = packbf(p[2], p[3]);
        pfu.u[2] = packbf(p[4], p[5]);
        pfu.u[3] = packbf(p[6], p[7]);
        short8 pf = pfu.s;
        #pragma unroll
        for (int ct = 0; ct < 8; ++ct) {
            short8 hf = *(const short8*)&hbuf[cur][ct * 16 + l15][g * 8];
            acc[ct] = __builtin_amdgcn_mfma_f32_16x16x32_bf16(hf, pf, acc[ct], 0, 0, 0);
        }
        if (jt < 15) {
            *(short8*)&hbuf[cur ^ 1][cS][ksS] = s0;
            *(short8*)&hbuf[cur ^ 1][cS][ksS + 8] = s1;
        }
        __syncthreads();
    }

    if (self) {
        unsigned short z0b = f2b(z0);
        short8 pfs;
        #pragma unroll
        for (int q = 0; q < 8; ++q)
            pfs[q] = (short)((g * 8 + q == l15) ? z0b : 0);
        int sc0 = side * 512 + i0;
        #pragma unroll
        for (int ct = 0; ct < 8; ++ct) {
            short8 hfs = *(const short8*)&HT[HTbase + (size_t)(ct * 16 + l15) * 1024 + sc0 + g * 8];
            acc[ct] = __builtin_amdgcn_mfma_f32_16x16x32_bf16(hfs, pfs, acc[ct], 0, 0, 0);
        }
    }

    zacc += __shfl_xor(zacc, 16, 64);
    zacc += __shfl_xor(zacc, 32, 64);
    float zinv = 1.f / zacc;

    if (mode == 0) {
        size_t orow = ((size_t)(b * 1024 + n)) * 512 + h * 128;
        #pragma unroll
        for (int ct = 0; ct < 8; ++ct) {
            int c0 = ct * 16 + g * 4;
            float o[4];
            #pragma unroll
            for (int r = 0; r < 4; ++r) {
                float v = acc[ct][r] * zinv;
                o[r] = v > 0.f ? v : __expf(v) - 1.f;
            }
            unsigned long long pv =
                  (unsigned long long)f2b(o[0])
                | ((unsigned long long)f2b(o[1]) << 16)
                | ((unsigned long long)f2b(o[2]) << 32)
                | ((unsigned long long)f2b(o[3]) << 48);
            *(unsigned long long*)&x2[orow + c0] = pv;
        }
    } else {
        float o[8][4];
        float mx = -3.0e38f;
        #pragma unroll
        for (int ct = 0; ct < 8; ++ct) {
            #pragma unroll
            for (int r = 0; r < 4; ++r) {
                float v = acc[ct][r] * zinv;
                v = v > 0.f ? v : __expf(v) - 1.f;
                o[ct][r] = v;
                mx = fmaxf(mx, v);
            }
        }
        mx = fmaxf(mx, __shfl_xor(mx, 16, 64));
        mx = fmaxf(mx, __shfl_xor(mx, 32, 64));
        float s = 0.f;
        #pragma unroll
        for (int ct = 0; ct < 8; ++ct)
            #pragma unroll
            for (int r = 0; r < 4; ++r) s += __expf(o[ct][r] - mx);
        s += __shfl_xor(s, 16, 64);
        s += __shfl_xor(s, 32, 64);
        float lse = mx + __logf(s);
        #pragma unroll
        for (int ct = 0; ct < 8; ++ct) {
            float4 st = {o[ct][0] - lse, o[ct][1] - lse, o[ct][2] - lse, o[ct][3] - lse};
            *(float4*)&dout[((size_t)(b * 512 + i)) * 128 + ct * 16 + g * 4] = st;
        }
    }
}

// ===================== cooperative mega-kernel =============================
__global__ __launch_bounds__(256, 2) void fused_kernel(
    const float* __restrict__ hs, const float* __restrict__ os,
    const float* __restrict__ Wh, const float* __restrict__ ah,
    const float* __restrict__ Wo, const float* __restrict__ ao,
    float* __restrict__ out, void* __restrict__ wsv)
{
    u16t* h1T = (u16t*)wsv;
    u16t* x2  = h1T + 4194304;
    u16t* h2T = x2 + 4194304;
    u16t* WhT = h2T + 1048576;
    u16t* WoT = WhT + 65536;
    u16t* xb  = WoT + 65536;
    float* f1a = (float*)(xb + 1048576);
    float* f2a = f1a + 32768;
    float* f1b = f2a + 32768;
    float* f2b_ = f1b + 8192;

    __shared__ __align__(16) u16t hbuf[2][128][40];
    __shared__ __align__(16) float f2s[512];
    __shared__ float red4[4];

    cg::grid_group grid = cg::this_grid();
    int bid = blockIdx.x, t = threadIdx.x;

    prep_body(bid * 256 + t, hs, os, Wh, Wo, WhT, WoT, xb);
    grid.sync();
    proj1_body(bid, t, xb, WhT, ah, h1T, f1a, f2a);
    grid.sync();
    attn_body(0, bid, t, h1T, f1a, f2a, x2, nullptr, hbuf, f2s, red4);
    grid.sync();
    if (bid < 128) proj2_body(bid, t, x2, WoT, ao, h2T, f1b, f2b_);
    grid.sync();
    if (bid < 64) attn_body(1, bid, t, h2T, f1b, f2b_, nullptr, out, hbuf, f2s, red4);
}

// ===================== fallback separate kernels ===========================
__global__ __launch_bounds__(256) void prep_kernel(
    const float* __restrict__ hs, const float* __restrict__ os,
    const float* __restrict__ Wh, const float* __restrict__ Wo,
    u16t* __restrict__ WhT, u16t* __restrict__ WoT, u16t* __restrict__ xb)
{
    prep_body(blockIdx.x * 256 + threadIdx.x, hs, os, Wh, Wo, WhT, WoT, xb);
}
__global__ __launch_bounds__(256) void proj1_kernel(
    const u16t* __restrict__ xb, const u16t* __restrict__ WhT,
    const float* __restrict__ ah,
    u16t* __restrict__ h1T, float* __restrict__ f1, float* __restrict__ f2)
{
    proj1_body(blockIdx.x, threadIdx.x, xb, WhT, ah, h1T, f1, f2);
}
__global__ __launch_bounds__(256) void proj2_kernel(
    const u16t* __restrict__ x2, const u16t* __restrict__ WoT,
    const float* __restrict__ ao,
    u16t* __restrict__ h2T, float* __restrict__ f1, float* __restrict__ f2)
{
    proj2_body(blockIdx.x, threadIdx.x, x2, WoT, ao, h2T, f1, f2);
}
__global__ __launch_bounds__(256) void attn_kernel(
    const u16t* __restrict__ HT,
    const float* __restrict__ f1, const float* __restrict__ f2,
    u16t* __restrict__ x2, float* __restrict__ dout, int mode)
{
    __shared__ __align__(16) u16t hbuf[2][128][40];
    __shared__ __align__(16) float f2s[512];
    __shared__ float red4[4];
    attn_body(mode, blockIdx.x, threadIdx.x, HT, f1, f2, x2, dout, hbuf, f2s, red4);
}

extern "C" void kernel_launch(void* const* d_in, const int* in_sizes, int n_in,
                              void* d_out, int out_size, void* d_ws, size_t ws_size,
                              hipStream_t stream)
{
    const float* hs = (const float*)d_in[0];
    const float* os = (const float*)d_in[1];
    const float* Wh = (const float*)d_in[4];
    const float* ah = (const float*)d_in[5];
    const float* Wo = (const float*)d_in[6];
    const float* ao = (const float*)d_in[7];
    float* out = (float*)d_out;
    void* wsv = d_ws;

    void* args[] = {(void*)&hs, (void*)&os, (void*)&Wh, (void*)&ah,
                    (void*)&Wo, (void*)&ao, (void*)&out, (void*)&wsv};
    hipError_t e = hipLaunchCooperativeKernel((const void*)fused_kernel,
                                              dim3(512), dim3(256), args, 0, stream);
    if (e != hipSuccess) {
        // fallback: 5-kernel path (identical math)
        u16t* h1T = (u16t*)d_ws;
        u16t* x2  = h1T + 4194304;
        u16t* h2T = x2 + 4194304;
        u16t* WhT = h2T + 1048576;
        u16t* WoT = WhT + 65536;
        u16t* xb  = WoT + 65536;
        float* f1a = (float*)(xb + 1048576);
        float* f2a = f1a + 32768;
        float* f1b = f2a + 32768;
        float* f2b_ = f1b + 8192;

        prep_kernel<<<512, 256, 0, stream>>>(hs, os, Wh, Wo, WhT, WoT, xb);
        proj1_kernel<<<512, 256, 0, stream>>>(xb, WhT, ah, h1T, f1a, f2a);
        attn_kernel<<<512, 256, 0, stream>>>(h1T, f1a, f2a, x2, nullptr, 0);
        proj2_kernel<<<128, 256, 0, stream>>>(x2, WoT, ao, h2T, f1b, f2b_);
        attn_kernel<<<64, 256, 0, stream>>>(h2T, f1b, f2b_, nullptr, out, 1);
    }
}

// Round 6
// 62.282 us; speedup vs baseline: 5.0456x; 5.0456x over previous
//
#include <hip/hip_runtime.h>

#define B 8
#define NH 512
#define D 128
#define HEADS 4
#define ALPHA 0.2f

typedef short short8 __attribute__((ext_vector_type(8)));
typedef float f32x4 __attribute__((ext_vector_type(4)));
typedef unsigned short u16t;

__device__ __forceinline__ unsigned short f2b(float f) {
    union { float f; unsigned u; } v; v.f = f;
    unsigned r = v.u + 0x7FFFu + ((v.u >> 16) & 1u);
    return (unsigned short)(r >> 16);
}
__device__ __forceinline__ float lrelu(float x) { return fmaxf(x, ALPHA * x); }
// pack two f32 -> two bf16 (truncation) in one v_perm
__device__ __forceinline__ unsigned packbf(float a, float b) {
    union { float f; unsigned u; } ua, ub; ua.f = a; ub.f = b;
    return __builtin_amdgcn_perm(ub.u, ua.u, 0x07060302u);
}
// pack two f32 -> two bf16 with RNE-ish rounding (matches f2b)
__device__ __forceinline__ unsigned packbf_rne(float a, float b) {
    return (unsigned)f2b(a) | ((unsigned)f2b(b) << 16);
}

// ============ proj1: h1T[bh][c][n] = (x @ Wh)^T, + f1a/f2a =================
// grid 512 (128 row-tiles of 64 x 4 heads), 256 thr.
// W[h] staged f32->bf16 transposed into LDS per block (kills prep kernel).
// Blocks bid<128 also emit global WoT[c][k] = bf16(Wo[k][c]) for proj2.
__global__ __launch_bounds__(256) void proj1_kernel(
    const float* __restrict__ hs, const float* __restrict__ os,
    const float* __restrict__ Wh, const float* __restrict__ Wo,
    const float* __restrict__ ah,
    u16t* __restrict__ h1T, u16t* __restrict__ WoT,
    float* __restrict__ f1, float* __restrict__ f2)
{
    int bid = blockIdx.x;
    int rt = bid >> 2, h = bid & 3;
    int rowG = rt * 64;
    int b = rowG >> 10;
    int t = threadIdx.x;
    int w = t >> 6, l = t & 63, l15 = l & 15, g = l >> 4;

    __shared__ __align__(16) u16t wlds[128][136];   // [c][k], pad 8 -> 34.8KB

    // stage W[h]^T into LDS: pair p -> (c = p&127, k0 = (p>>7)*2)
    {
        const float* Whh = Wh + (size_t)h * 16384;
        #pragma unroll
        for (int i = 0; i < 32; ++i) {
            int p = i * 256 + t;
            int c = p & 127, k0 = (p >> 7) * 2;
            float w0 = Whh[(size_t)k0 * 128 + c];
            float w1 = Whh[(size_t)(k0 + 1) * 128 + c];
            *(unsigned*)&wlds[c][k0] = packbf_rne(w0, w1);
        }
    }
    // side job: emit WoT for proj2 (128 blocks x 256 thr x 2 elems = 65536)
    if (bid < 128) {
        int idx = bid * 512 + t * 2;
        int c = idx >> 9, k = idx & 511;
        float w0 = Wo[(size_t)k * 128 + c];
        float w1 = Wo[(size_t)(k + 1) * 128 + c];
        *(unsigned*)&WoT[(size_t)c * 512 + k] = packbf_rne(w0, w1);
    }
    __syncthreads();

    // A row: convert f32 x on the fly
    int nA = rowG + w * 16 + l15;
    int nloc = nA & 1023;
    const float* xr = (nloc < NH) ? hs + ((size_t)(b * NH + nloc)) * 128
                                  : os + ((size_t)(b * NH + (nloc - NH))) * 128;

    f32x4 acc[8] = {};
    #pragma unroll
    for (int kc = 0; kc < 4; ++kc) {
        int k0 = kc * 32 + g * 8;
        float4 u0 = *(const float4*)&xr[k0];
        float4 u1 = *(const float4*)&xr[k0 + 4];
        union { unsigned u[4]; short8 s; } afu;
        afu.u[0] = packbf_rne(u0.x, u0.y);
        afu.u[1] = packbf_rne(u0.z, u0.w);
        afu.u[2] = packbf_rne(u1.x, u1.y);
        afu.u[3] = packbf_rne(u1.z, u1.w);
        short8 af = afu.s;
        #pragma unroll
        for (int ct = 0; ct < 8; ++ct) {
            short8 bfr = *(const short8*)&wlds[ct * 16 + l15][k0];
            acc[ct] = __builtin_amdgcn_mfma_f32_16x16x32_bf16(af, bfr, acc[ct], 0, 0, 0);
        }
    }

    int bh = b * HEADS + h;
    size_t hTbase = (size_t)bh * 131072;
    int nloc0 = (rowG & 1023) + w * 16 + g * 4;
    float pr1[4] = {0.f, 0.f, 0.f, 0.f}, pr2[4] = {0.f, 0.f, 0.f, 0.f};

    #pragma unroll
    for (int ct = 0; ct < 8; ++ct) {
        int c = ct * 16 + l15;
        unsigned long long pv =
              (unsigned long long)f2b(acc[ct][0])
            | ((unsigned long long)f2b(acc[ct][1]) << 16)
            | ((unsigned long long)f2b(acc[ct][2]) << 32)
            | ((unsigned long long)f2b(acc[ct][3]) << 48);
        *(unsigned long long*)&h1T[hTbase + (size_t)c * 1024 + nloc0] = pv;
        float a1 = ah[h * 256 + c], a2 = ah[h * 256 + 128 + c];
        #pragma unroll
        for (int r = 0; r < 4; ++r) {
            pr1[r] = fmaf(acc[ct][r], a1, pr1[r]);
            pr2[r] = fmaf(acc[ct][r], a2, pr2[r]);
        }
    }
    #pragma unroll
    for (int r = 0; r < 4; ++r) {
        float v1 = pr1[r], v2 = pr2[r];
        #pragma unroll
        for (int m = 1; m <= 8; m <<= 1) {
            v1 += __shfl_xor(v1, m, 64);
            v2 += __shfl_xor(v2, m, 64);
        }
        if (l15 == 0) {
            f1[(size_t)bh * 1024 + nloc0 + r] = v1;
            f2[(size_t)bh * 1024 + nloc0 + r] = v2;
        }
    }
}

// ============ proj2: h2T[b][c][n] = (x2 @ Wo)^T, + f1b/f2b =================
// grid 128 (8192 rows / 64), 256 thr. x2 bf16 row-major [8192][512].
__global__ __launch_bounds__(256) void proj2_kernel(
    const u16t* __restrict__ x2, const u16t* __restrict__ WoT,
    const float* __restrict__ ao,
    u16t* __restrict__ h2T, float* __restrict__ f1, float* __restrict__ f2)
{
    int rowG = blockIdx.x * 64;
    int b = rowG >> 10;
    int t = threadIdx.x;
    int w = t >> 6, l = t & 63, l15 = l & 15, g = l >> 4;

    int rowA = rowG + w * 16 + l15;

    f32x4 acc[8] = {};
    #pragma unroll
    for (int kc = 0; kc < 16; ++kc) {
        int k0 = kc * 32 + g * 8;
        short8 af = *(const short8*)&x2[(size_t)rowA * 512 + k0];
        #pragma unroll
        for (int ct = 0; ct < 8; ++ct) {
            short8 bfr = *(const short8*)&WoT[(ct * 16 + l15) * 512 + k0];
            acc[ct] = __builtin_amdgcn_mfma_f32_16x16x32_bf16(af, bfr, acc[ct], 0, 0, 0);
        }
    }

    size_t hTbase = (size_t)b * 131072;
    int nloc0 = (rowG & 1023) + w * 16 + g * 4;
    int rowOut0 = rowG + w * 16 + g * 4;
    float pr1[4] = {0.f, 0.f, 0.f, 0.f}, pr2[4] = {0.f, 0.f, 0.f, 0.f};

    #pragma unroll
    for (int ct = 0; ct < 8; ++ct) {
        int c = ct * 16 + l15;
        unsigned long long pv =
              (unsigned long long)f2b(acc[ct][0])
            | ((unsigned long long)f2b(acc[ct][1]) << 16)
            | ((unsigned long long)f2b(acc[ct][2]) << 32)
            | ((unsigned long long)f2b(acc[ct][3]) << 48);
        *(unsigned long long*)&h2T[hTbase + (size_t)c * 1024 + nloc0] = pv;
        float a1 = ao[c], a2 = ao[128 + c];
        #pragma unroll
        for (int r = 0; r < 4; ++r) {
            pr1[r] = fmaf(acc[ct][r], a1, pr1[r]);
            pr2[r] = fmaf(acc[ct][r], a2, pr2[r]);
        }
    }
    #pragma unroll
    for (int r = 0; r < 4; ++r) {
        float v1 = pr1[r], v2 = pr2[r];
        #pragma unroll
        for (int m = 1; m <= 8; m <<= 1) {
            v1 += __shfl_xor(v1, m, 64);
            v2 += __shfl_xor(v2, m, 64);
        }
        if (l15 == 0) { f1[rowOut0 + r] = v1; f2[rowOut0 + r] = v2; }
    }
}

// ============ attn: O^T = H^T · P^T (MFMA), self via diagonal MFMA =========
// mode 0: 512 blocks (XCD-swizzled: 64 q=(z,side) x 8 itiles of 64 rows)
// mode 1: 64 blocks (8 b x 8 itiles), + fused elu+log_softmax
__global__ __launch_bounds__(256) void attn_kernel(
    const u16t* __restrict__ HT,                    // [Z][128][1024] bf16
    const float* __restrict__ f1, const float* __restrict__ f2,  // [Z][1024]
    u16t* __restrict__ x2, float* __restrict__ dout, int mode)
{
    __shared__ __align__(16) u16t hbuf[2][128][40];
    __shared__ __align__(16) float f2s[512];
    __shared__ float red4[4];

    int t = threadIdx.x, w4 = t >> 6, l = t & 63, l15 = l & 15, g = l >> 4;
    int wid = blockIdx.x;
    int itile, side, z, b, h;
    if (mode == 0) {
        int xcd = wid & 7, jj = (wid >> 3) & 7;
        itile = wid >> 6;
        int q = xcd * 8 + jj;
        z = q >> 1; side = q & 1; b = z >> 2; h = z & 3;
    } else {
        b = wid & 7; itile = wid >> 3; side = 0; z = b; h = 0;
    }
    bool self = (side == 0);
    int nbBase = self ? 512 : 0;
    size_t HTbase = (size_t)z * 131072;
    size_t fbase = (size_t)z * 1024;

    f2s[t] = f2[fbase + nbBase + t];
    f2s[t + 256] = f2[fbase + nbBase + t + 256];
    __syncthreads();
    float mv = fmaxf(f2s[t], f2s[t + 256]);
    #pragma unroll
    for (int m = 1; m <= 32; m <<= 1) mv = fmaxf(mv, __shfl_xor(mv, m, 64));
    if (l == 0) red4[w4] = mv;
    __syncthreads();
    float M = fmaxf(fmaxf(red4[0], red4[1]), fmaxf(red4[2], red4[3]));

    int i0 = itile * 64 + w4 * 16;
    int i = i0 + l15;
    int n = side * 512 + i;
    float fv = f1[fbase + n];
    float mr = lrelu(fv + M);
    float z0 = 0.f;
    if (self) {
        float sc = lrelu(fv + f2[fbase + i]);
        mr = fmaxf(mr, sc);
        z0 = __expf(sc - mr);
    }
    float zacc = (g == 0) ? z0 : 0.f;

    {
        int c = t >> 1, ks = (t & 1) * 16;
        const u16t* src = &HT[HTbase + (size_t)c * 1024 + nbBase + ks];
        *(short8*)&hbuf[0][c][ks] = *(const short8*)src;
        *(short8*)&hbuf[0][c][ks + 8] = *(const short8*)(src + 8);
    }
    __syncthreads();

    f32x4 acc[8] = {};
    int cS = t >> 1, ksS = (t & 1) * 16;

    for (int jt = 0; jt < 16; ++jt) {
        int cur = jt & 1;
        short8 s0, s1;
        if (jt < 15) {
            const u16t* src = &HT[HTbase + (size_t)cS * 1024 + nbBase + (jt + 1) * 32 + ksS];
            s0 = *(const short8*)src;
            s1 = *(const short8*)(src + 8);
        }
        int j0 = jt * 32 + g * 8;
        float p[8];
        #pragma unroll
        for (int q = 0; q < 8; ++q) {
            float tq = fv + f2s[j0 + q];
            float ev = fmaxf(tq, ALPHA * tq);
            p[q] = __expf(ev - mr);
            zacc += p[q];
        }
        union { unsigned u[4]; short8 s; } pfu;
        pfu.u[0] = packbf(p[0], p[1]);
        pfu.u[1] = packbf(p[2], p[3]);
        pfu.u[2] = packbf(p[4], p[5]);
        pfu.u[3] = packbf(p[6], p[7]);
        short8 pf = pfu.s;
        #pragma unroll
        for (int ct = 0; ct < 8; ++ct) {
            short8 hf = *(const short8*)&hbuf[cur][ct * 16 + l15][g * 8];
            acc[ct] = __builtin_amdgcn_mfma_f32_16x16x32_bf16(hf, pf, acc[ct], 0, 0, 0);
        }
        if (jt < 15) {
            *(short8*)&hbuf[cur ^ 1][cS][ksS] = s0;
            *(short8*)&hbuf[cur ^ 1][cS][ksS + 8] = s1;
        }
        __syncthreads();
    }

    if (self) {
        unsigned short z0b = f2b(z0);
        short8 pfs;
        #pragma unroll
        for (int q = 0; q < 8; ++q)
            pfs[q] = (short)((g * 8 + q == l15) ? z0b : 0);
        int sc0 = side * 512 + i0;
        #pragma unroll
        for (int ct = 0; ct < 8; ++ct) {
            short8 hfs = *(const short8*)&HT[HTbase + (size_t)(ct * 16 + l15) * 1024 + sc0 + g * 8];
            acc[ct] = __builtin_amdgcn_mfma_f32_16x16x32_bf16(hfs, pfs, acc[ct], 0, 0, 0);
        }
    }

    zacc += __shfl_xor(zacc, 16, 64);
    zacc += __shfl_xor(zacc, 32, 64);
    float zinv = 1.f / zacc;

    if (mode == 0) {
        size_t orow = ((size_t)(b * 1024 + n)) * 512 + h * 128;
        #pragma unroll
        for (int ct = 0; ct < 8; ++ct) {
            int c0 = ct * 16 + g * 4;
            float o[4];
            #pragma unroll
            for (int r = 0; r < 4; ++r) {
                float v = acc[ct][r] * zinv;
                o[r] = v > 0.f ? v : __expf(v) - 1.f;
            }
            unsigned long long pv =
                  (unsigned long long)f2b(o[0])
                | ((unsigned long long)f2b(o[1]) << 16)
                | ((unsigned long long)f2b(o[2]) << 32)
                | ((unsigned long long)f2b(o[3]) << 48);
            *(unsigned long long*)&x2[orow + c0] = pv;
        }
    } else {
        float o[8][4];
        float mx = -3.0e38f;
        #pragma unroll
        for (int ct = 0; ct < 8; ++ct) {
            #pragma unroll
            for (int r = 0; r < 4; ++r) {
                float v = acc[ct][r] * zinv;
                v = v > 0.f ? v : __expf(v) - 1.f;
                o[ct][r] = v;
                mx = fmaxf(mx, v);
            }
        }
        mx = fmaxf(mx, __shfl_xor(mx, 16, 64));
        mx = fmaxf(mx, __shfl_xor(mx, 32, 64));
        float s = 0.f;
        #pragma unroll
        for (int ct = 0; ct < 8; ++ct)
            #pragma unroll
            for (int r = 0; r < 4; ++r) s += __expf(o[ct][r] - mx);
        s += __shfl_xor(s, 16, 64);
        s += __shfl_xor(s, 32, 64);
        float lse = mx + __logf(s);
        #pragma unroll
        for (int ct = 0; ct < 8; ++ct) {
            float4 st = {o[ct][0] - lse, o[ct][1] - lse, o[ct][2] - lse, o[ct][3] - lse};
            *(float4*)&dout[((size_t)(b * 512 + i)) * 128 + ct * 16 + g * 4] = st;
        }
    }
}

extern "C" void kernel_launch(void* const* d_in, const int* in_sizes, int n_in,
                              void* d_out, int out_size, void* d_ws, size_t ws_size,
                              hipStream_t stream)
{
    const float* hs = (const float*)d_in[0];
    const float* os = (const float*)d_in[1];
    const float* Wh = (const float*)d_in[4];
    const float* ah = (const float*)d_in[5];
    const float* Wo = (const float*)d_in[6];
    const float* ao = (const float*)d_in[7];
    float* out = (float*)d_out;

    u16t* h1T = (u16t*)d_ws;             // 4,194,304
    u16t* x2  = h1T + 4194304;           // 4,194,304
    u16t* h2T = x2 + 4194304;            // 1,048,576
    u16t* WoT = h2T + 1048576;           // 65,536
    float* f1a = (float*)(WoT + 65536);  // 32,768
    float* f2a = f1a + 32768;
    float* f1b = f2a + 32768;            // 8,192
    float* f2b_ = f1b + 8192;

    proj1_kernel<<<512, 256, 0, stream>>>(hs, os, Wh, Wo, ah, h1T, WoT, f1a, f2a);
    attn_kernel<<<512, 256, 0, stream>>>(h1T, f1a, f2a, x2, nullptr, 0);
    proj2_kernel<<<128, 256, 0, stream>>>(x2, WoT, ao, h2T, f1b, f2b_);
    attn_kernel<<<64, 256, 0, stream>>>(h2T, f1b, f2b_, nullptr, out, 1);
}